// Round 12
// baseline (10395.979 us; speedup 1.0000x reference)
//
#include <hip/hip_runtime.h>
#include <math.h>

// ---------------------------------------------------------------------------
// Seq2SeqLSTM on MI355X -- Round 11: persistent decoder, xp layout fix + NT.
//
// R10 regression diagnosis: role A's xp read was uncoalesced sc1
// ([p][j][r] layout, lane-stride 256B -> 64KB overfetch/step/WG, FETCH
// 2.27GB) on the critical path; P's Wout stream thrashed chain L2.
// R11: xp -> [p][r][j] (A reads contiguous 4KB); sc1 only at first touch
// (p==t, just written by P cross-XCD); plain cached for the 30x replays
// (immutable, never stale-cached by construction). P uses nontemporal
// Wout loads + dout stores to protect chain L2. Choreography unchanged
// (R10-proven: absmax exact).
// ---------------------------------------------------------------------------

#define B     64
#define SLEN  64
#define TLEN  32
#define HID   256
#define EMBD  256
#define G4    1024
#define VOC   32000
#define NPRED 31
#define FBASE 64        // flag value after encoder (64 positions)

typedef unsigned long long u64;

__device__ __forceinline__ float sigf(float x){ return 1.0f/(1.0f+__expf(-x)); }

__device__ __forceinline__ void gstoref(float* p, float v){
  __hip_atomic_store(p, v, __ATOMIC_RELAXED, __HIP_MEMORY_SCOPE_AGENT);
}
__device__ __forceinline__ void gstorei(int* p, int v){
  __hip_atomic_store(p, v, __ATOMIC_RELAXED, __HIP_MEMORY_SCOPE_AGENT);
}
__device__ __forceinline__ float gloadf(const float* p){
  return __hip_atomic_load(p, __ATOMIC_RELAXED, __HIP_MEMORY_SCOPE_AGENT);
}
__device__ __forceinline__ int gload32(const int* p){
  return __hip_atomic_load(p, __ATOMIC_RELAXED, __HIP_MEMORY_SCOPE_AGENT);
}

// --------------------------------- zero ------------------------------------
__global__ void k_zero(int* __restrict__ p){
  p[threadIdx.x] = 0;    // block 512
}

// ------------------------------- transpose ----------------------------------
__global__ __launch_bounds__(256) void k_tr(const float* __restrict__ src,
                                            float* __restrict__ dst){
  __shared__ float t[64][65];
  const int r0 = blockIdx.x*64, c0 = blockIdx.y*64;
  const int lr = threadIdx.x>>6, lc = threadIdx.x&63;
  #pragma unroll
  for (int i=0;i<16;i++){
    int r = lr + i*4;
    t[r][lc] = src[(size_t)(r0+r)*256 + c0+lc];
  }
  __syncthreads();
  #pragma unroll
  for (int i=0;i<16;i++){
    int c = lr + i*4;
    dst[(size_t)(c0+c)*1024 + r0+lc] = t[lc][c];
  }
}

// --------------------------------- xproj -----------------------------------
// NEW layout: out[(pos*64 + r)*G4 + j] = b0[j] + sum_k emb[tok[r]][k]*W[j][k]
__global__ __launch_bounds__(256) void k_xproj(
    const int* __restrict__ tok, int tok_stride, int pos0,
    const float* __restrict__ emb, const float* __restrict__ W,
    const float* __restrict__ b0, float* __restrict__ out)
{
  __shared__ float xT[128][64];
  const int tid  = threadIdx.x;
  const int lane = tid & 63;
  const int wv   = __builtin_amdgcn_readfirstlane(tid >> 6);
  const int pos  = pos0 + blockIdx.y;
  const int jbase= blockIdx.x*32 + wv*8;

  const int rS = tid >> 2, klane = tid & 3;
  const int tokrow = tok[rS*tok_stride + pos];
  const float* xsrc = emb + (size_t)tokrow*EMBD;

  float acc[8];
  #pragma unroll
  for (int jj=0;jj<8;jj++) acc[jj]=0.f;

  for (int c=0;c<2;c++){
    __syncthreads();
    #pragma unroll
    for (int i=0;i<32;i++){
      int k = klane + 4*i;
      xT[k][rS] = xsrc[c*128 + k];
    }
    __syncthreads();
    for (int kc=0;kc<8;kc++){
      float x[16];
      #pragma unroll
      for (int i=0;i<16;i++) x[i] = xT[kc*16+i][lane];
      #pragma unroll
      for (int jj=0;jj<8;jj++){
        const float* Wp = W + (size_t)(jbase+jj)*EMBD + c*128 + kc*16;
        float s = 0.f;
        #pragma unroll
        for (int i=0;i<16;i++) s += Wp[i]*x[i];
        acc[jj] += s;
      }
    }
  }
  #pragma unroll
  for (int jj=0;jj<8;jj++){
    int j = jbase+jj;
    out[((size_t)pos*64 + lane)*G4 + j] = acc[jj] + b0[j];
  }
}

// ------------------------------- dotpart ------------------------------------
__device__ __forceinline__ float4 dotpart(const float4* __restrict__ Wq,
                                          const float* __restrict__ hs,
                                          int kq, int jg){
  float ax=0.f, ay=0.f, az=0.f, aw=0.f;
  const float4* __restrict__ hq = (const float4*)(hs + (kq<<6));
  const float4* __restrict__ w  = Wq + (size_t)(kq<<6)*256 + jg;
  #pragma unroll 4
  for (int kk=0; kk<16; ++kk){
    float4 h4 = hq[kk];
    float4 w0 = w[0];
    float4 w1 = w[256];
    float4 w2 = w[512];
    float4 w3 = w[768];
    ax += w0.x*h4.x; ay += w0.y*h4.x; az += w0.z*h4.x; aw += w0.w*h4.x;
    ax += w1.x*h4.y; ay += w1.y*h4.y; az += w1.z*h4.y; aw += w1.w*h4.y;
    ax += w2.x*h4.z; ay += w2.y*h4.z; az += w2.z*h4.z; aw += w2.w*h4.z;
    ax += w3.x*h4.w; ay += w3.y*h4.w; az += w3.z*h4.w; aw += w3.w*h4.w;
    w += 1024;
  }
  return make_float4(ax,ay,az,aw);
}

// --------------------------- encoder pipe (R8) -------------------------------
__global__ __launch_bounds__(1024) void k_pipe(
    const float* __restrict__ xp, int nsteps,
    const float* __restrict__ WT0, const float* __restrict__ WT1i,
    const float* __restrict__ WT1h, const float* __restrict__ b1,
    float* __restrict__ h0P, float* __restrict__ h1P,
    float* __restrict__ c0P, float* __restrict__ c1P,
    float* __restrict__ h0R, float* __restrict__ p1R,
    int* __restrict__ fA, int* __restrict__ fB1, int* __restrict__ fB2,
    int fbase, int initzero)
{
  __shared__ __align__(16) float part[4][4096];
  __shared__ float xps[1024];
  __shared__ __align__(16) float hloc[256];
  __shared__ float padL[4096];
  const int tid  = threadIdx.x;
  const int kq   = tid >> 8, jg = tid & 255;
  const int role = blockIdx.x >> 6;
  const int r    = blockIdx.x & 63;
  if (nsteps < 0){ padL[tid] = xp[tid]; h0R[tid] = padL[tid ^ 1]; }

  if (role == 0){
    float c0 = 0.f;
    if (tid < HID){
      if (initzero){ c0 = 0.f; hloc[tid] = 0.f; }
      else { c0 = c0P[tid*64 + r]; hloc[tid] = h0P[tid*64 + r]; }
    }
    __syncthreads();
    const float4* W4 = (const float4*)WT0;
    for (int q = 0; q < nsteps; ++q){
      float xv = xp[((size_t)q*64 + r)*G4 + tid];   // coalesced 4KB
      if (tid == 0 && q >= 4){
        int tgt = fbase + q - 3, g = 0;
        while (gload32(fB1 + r) < tgt && ++g < (1<<24)) {}
      }
      float4 a = dotpart(W4, hloc, kq, jg);
      xps[tid] = xv;
      *(float4*)&part[kq][jg<<2] = a;
      __syncthreads();
      if (tid < HID){
        float g0 = part[0][tid]+part[1][tid]+part[2][tid]+part[3][tid] + xps[tid];
        float g1 = part[0][HID+tid]+part[1][HID+tid]+part[2][HID+tid]+part[3][HID+tid] + xps[HID+tid];
        float g2 = part[0][2*HID+tid]+part[1][2*HID+tid]+part[2][2*HID+tid]+part[3][2*HID+tid] + xps[2*HID+tid];
        float g3 = part[0][3*HID+tid]+part[1][3*HID+tid]+part[2][3*HID+tid]+part[3][3*HID+tid] + xps[3*HID+tid];
        c0 = sigf(g1)*c0 + sigf(g0)*tanhf(g2);
        float h = sigf(g3)*tanhf(c0);
        hloc[tid] = h;
        gstoref(h0R + (q&3)*16384 + r*256 + tid, h);
        asm volatile("s_waitcnt vmcnt(0)" ::: "memory");
      }
      __syncthreads();
      if (tid == 0) gstorei(fA + r, fbase + q + 1);
    }
    if (tid < HID){ c0P[tid*64 + r] = c0; h0P[tid*64 + r] = hloc[tid]; }
  }
  else if (role == 1){
    const float4* W4 = (const float4*)WT1i;
    for (int q = 0; q < nsteps; ++q){
      if (tid == 0){
        int tgt = fbase + q + 1, g = 0;
        while (gload32(fA + r) < tgt && ++g < (1<<24)) {}
        if (q >= 4){
          int t2 = fbase + q - 3; g = 0;
          while (gload32(fB2 + r) < t2 && ++g < (1<<24)) {}
        }
      }
      __syncthreads();
      if (tid < HID) hloc[tid] = gloadf(h0R + (q&3)*16384 + r*256 + tid);
      __syncthreads();
      float4 a = dotpart(W4, hloc, kq, jg);
      *(float4*)&part[kq][jg<<2] = a;
      __syncthreads();
      float p = part[0][tid]+part[1][tid]+part[2][tid]+part[3][tid];
      gstoref(p1R + (q&3)*65536 + r*1024 + tid, p);
      asm volatile("s_waitcnt vmcnt(0)" ::: "memory");
      __syncthreads();
      if (tid == 0) gstorei(fB1 + r, fbase + q + 1);
    }
  }
  else {
    float c1 = 0.f, bb0=0.f, bb1=0.f, bb2=0.f, bb3=0.f;
    if (tid < HID){
      bb0 = b1[tid]; bb1 = b1[HID+tid]; bb2 = b1[2*HID+tid]; bb3 = b1[3*HID+tid];
      if (initzero){ c1 = 0.f; hloc[tid] = 0.f; }
      else { c1 = c1P[tid*64 + r]; hloc[tid] = h1P[tid*64 + r]; }
    }
    __syncthreads();
    const float4* W4 = (const float4*)WT1h;
    for (int q = 0; q < nsteps; ++q){
      if (tid == 0){
        int tgt = fbase + q + 1, g = 0;
        while (gload32(fB1 + r) < tgt && ++g < (1<<24)) {}
      }
      __syncthreads();
      xps[tid] = gloadf(p1R + (q&3)*65536 + r*1024 + tid);
      asm volatile("s_waitcnt vmcnt(0)" ::: "memory");
      __syncthreads();
      if (tid == 0) gstorei(fB2 + r, fbase + q + 1);
      float4 a = dotpart(W4, hloc, kq, jg);
      *(float4*)&part[kq][jg<<2] = a;
      __syncthreads();
      if (tid < HID){
        float g0 = part[0][tid]+part[1][tid]+part[2][tid]+part[3][tid] + xps[tid] + bb0;
        float g1 = part[0][HID+tid]+part[1][HID+tid]+part[2][HID+tid]+part[3][HID+tid] + xps[HID+tid] + bb1;
        float g2 = part[0][2*HID+tid]+part[1][2*HID+tid]+part[2][2*HID+tid]+part[3][2*HID+tid] + xps[2*HID+tid] + bb2;
        float g3 = part[0][3*HID+tid]+part[1][3*HID+tid]+part[2][3*HID+tid]+part[3][3*HID+tid] + xps[3*HID+tid] + bb3;
        c1 = sigf(g1)*c1 + sigf(g0)*tanhf(g2);
        float h = sigf(g3)*tanhf(c1);
        hloc[tid] = h;
        if (q == nsteps-1) h1P[tid*64 + r] = h;
      }
      __syncthreads();
    }
    if (tid < HID) c1P[tid*64 + r] = c1;
  }
}

// ------------------------- persistent decoder --------------------------------
// flags: fA[0..63] fB1[64..127] fB2[128..191] fH[192..255] fP[256..319]
//        fX[320..383] fT[384]
__global__ __launch_bounds__(1024) void k_megadec(
    float* xp,                             // xp_d [32][64][1024] (RW)
    const float* __restrict__ WT0, const float* __restrict__ WT1i,
    const float* __restrict__ WT1h, const float* __restrict__ b1,
    const float* __restrict__ Wih0, const float* __restrict__ b0,
    const float* __restrict__ emb,
    const float* __restrict__ Wout, const float* __restrict__ bout,
    float* __restrict__ dout,
    const float* __restrict__ h0P, const float* __restrict__ h1P,
    const float* __restrict__ c0P, const float* __restrict__ c1P,
    float* __restrict__ h0R, float* __restrict__ p1R, float* __restrict__ h1R,
    float* __restrict__ pPv, int* __restrict__ pPi, float* __restrict__ xeG,
    int* __restrict__ flags)
{
  __shared__ __align__(16) float part[4][4096];   // 64 KB
  __shared__ float xps[1024];                     //  4 KB
  __shared__ __align__(16) float hloc[256];       //  1 KB
  __shared__ int   iscr[1024];                    //  4 KB
  __shared__ float htp[256*65];                   // 65 KB (padded [k][r])

  int* fA = flags;        int* fB1 = flags + 64;  int* fB2 = flags + 128;
  int* fH = flags + 192;  int* fP  = flags + 256; int* fX  = flags + 320;
  int* fT = flags + 384;

  const int tid  = threadIdx.x;
  const int lane = tid & 63;
  const int wv   = __builtin_amdgcn_readfirstlane(tid >> 6);
  const int kq   = tid >> 8, jg = tid & 255;
  const int role = blockIdx.x >> 6;
  const int r    = blockIdx.x & 63;

  // =========================== role A: layer 0 =============================
  if (role == 0){
    float c0 = 0.f;
    if (tid < HID){ c0 = c0P[tid*64 + r]; hloc[tid] = h0P[tid*64 + r]; }
    __syncthreads();
    const float4* W4 = (const float4*)WT0;
    int cum = 0;
    for (int t = 0; t < NPRED; ++t)
    for (int p = 0; p <= t; ++p, ++cum){
      if (wv == 0){
        if (lane == 0 && cum >= 4){
          int tgt = FBASE + cum - 3, g = 0;
          while (gload32(fB1 + r) < tgt && ++g < (1<<24)) {}
        }
        if (p == t && t >= 1){
          int g = 0;
          while (!__all(gload32(fX + lane) >= t) && ++g < (1<<24)) {}
        }
      }
      __syncthreads();
      const float* xa = xp + ((size_t)p*64 + r)*G4 + tid;   // coalesced
      float xv = (p == t) ? gloadf(xa) : *xa;   // sc1 first touch only
      float4 a = dotpart(W4, hloc, kq, jg);
      xps[tid] = xv;
      *(float4*)&part[kq][jg<<2] = a;
      __syncthreads();
      if (tid < HID){
        float g0 = part[0][tid]+part[1][tid]+part[2][tid]+part[3][tid] + xps[tid];
        float g1 = part[0][HID+tid]+part[1][HID+tid]+part[2][HID+tid]+part[3][HID+tid] + xps[HID+tid];
        float g2 = part[0][2*HID+tid]+part[1][2*HID+tid]+part[2][2*HID+tid]+part[3][2*HID+tid] + xps[2*HID+tid];
        float g3 = part[0][3*HID+tid]+part[1][3*HID+tid]+part[2][3*HID+tid]+part[3][3*HID+tid] + xps[3*HID+tid];
        c0 = sigf(g1)*c0 + sigf(g0)*tanhf(g2);
        float h = sigf(g3)*tanhf(c0);
        hloc[tid] = h;
        gstoref(h0R + (cum&3)*16384 + r*256 + tid, h);
        asm volatile("s_waitcnt vmcnt(0)" ::: "memory");
      }
      __syncthreads();
      if (tid == 0) gstorei(fA + r, FBASE + cum + 1);
    }
  }
  // =========================== role B1: Wih1.h0 ============================
  else if (role == 1){
    const float4* W4 = (const float4*)WT1i;
    int cum = 0;
    for (int t = 0; t < NPRED; ++t)
    for (int p = 0; p <= t; ++p, ++cum){
      if (tid == 0){
        int tgt = FBASE + cum + 1, g = 0;
        while (gload32(fA + r) < tgt && ++g < (1<<24)) {}
        if (cum >= 4){
          int t2 = FBASE + cum - 3; g = 0;
          while (gload32(fB2 + r) < t2 && ++g < (1<<24)) {}
        }
      }
      __syncthreads();
      if (tid < HID) hloc[tid] = gloadf(h0R + (cum&3)*16384 + r*256 + tid);
      __syncthreads();
      float4 a = dotpart(W4, hloc, kq, jg);
      *(float4*)&part[kq][jg<<2] = a;
      __syncthreads();
      float pp = part[0][tid]+part[1][tid]+part[2][tid]+part[3][tid];
      gstoref(p1R + (cum&3)*65536 + r*1024 + tid, pp);
      asm volatile("s_waitcnt vmcnt(0)" ::: "memory");
      __syncthreads();
      if (tid == 0) gstorei(fB1 + r, FBASE + cum + 1);
    }
  }
  // ================== role B2: Whh1.h1 + combine + act =====================
  else if (role == 2){
    float c1 = 0.f, bb0=0.f, bb1=0.f, bb2=0.f, bb3=0.f;
    if (tid < HID){
      bb0 = b1[tid]; bb1 = b1[HID+tid]; bb2 = b1[2*HID+tid]; bb3 = b1[3*HID+tid];
      c1 = c1P[tid*64 + r]; hloc[tid] = h1P[tid*64 + r];
    }
    __syncthreads();
    const float4* W4 = (const float4*)WT1h;
    int cum = 0;
    for (int t = 0; t < NPRED; ++t)
    for (int p = 0; p <= t; ++p, ++cum){
      if (tid == 0){
        int tgt = FBASE + cum + 1, g = 0;
        while (gload32(fB1 + r) < tgt && ++g < (1<<24)) {}
      }
      __syncthreads();
      xps[tid] = gloadf(p1R + (cum&3)*65536 + r*1024 + tid);
      asm volatile("s_waitcnt vmcnt(0)" ::: "memory");
      __syncthreads();
      if (tid == 0) gstorei(fB2 + r, FBASE + cum + 1);
      float4 a = dotpart(W4, hloc, kq, jg);
      *(float4*)&part[kq][jg<<2] = a;
      __syncthreads();
      if (tid < HID){
        float g0 = part[0][tid]+part[1][tid]+part[2][tid]+part[3][tid] + xps[tid] + bb0;
        float g1 = part[0][HID+tid]+part[1][HID+tid]+part[2][HID+tid]+part[3][HID+tid] + xps[HID+tid] + bb1;
        float g2 = part[0][2*HID+tid]+part[1][2*HID+tid]+part[2][2*HID+tid]+part[3][2*HID+tid] + xps[2*HID+tid] + bb2;
        float g3 = part[0][3*HID+tid]+part[1][3*HID+tid]+part[2][3*HID+tid]+part[3][3*HID+tid] + xps[3*HID+tid] + bb3;
        c1 = sigf(g1)*c1 + sigf(g0)*tanhf(g2);
        float h = sigf(g3)*tanhf(c1);
        hloc[tid] = h;
      }
      __syncthreads();
      if (p == t){
        if (tid == 0 && t >= 2){
          int g = 0;
          while (gload32(fT) < t - 1 && ++g < (1<<24)) {}
        }
        __syncthreads();
        if (tid < HID){
          gstoref(h1R + (t&1)*16384 + r*256 + tid, hloc[tid]);   // [r][k]
          asm volatile("s_waitcnt vmcnt(0)" ::: "memory");
        }
        __syncthreads();
        if (tid == 0) gstorei(fH + r, t + 1);
      }
    }
  }
  // ================== role P: pred + argmax + xproj ========================
  else {
    const int v  = r;                 // vocab slice id 0..63
    const int v0 = v * 500;
    const int rr = tid >> 4;          // 0..63  (row, for xproj)
    const int jl = tid & 15;          // 0..15  (j within slice)
    const float b0v = b0[v*16 + jl];

    for (int t = 0; t < NPRED; ++t){
      if (wv == 0){
        int g = 0;
        while (!__all(gload32(fH + lane) >= t+1) && ++g < (1<<24))
          __builtin_amdgcn_s_sleep(4);
      }
      if (tid == 0 && t >= 2){
        int g = 0;
        while (gload32(fT) < t - 1 && ++g < (1<<24)) {}
      }
      __syncthreads();
      // stage h1R[t&1] ([r][k]) -> htp[k*65+r]
      {
        const float* src = h1R + (size_t)(t&1)*16384;
        #pragma unroll
        for (int i=0;i<16;i++){
          int idx = tid + i*1024;
          float vl = gloadf(src + idx);
          htp[(idx & 255)*65 + (idx >> 8)] = vl;
        }
      }
      __syncthreads();
      // pred: wave wv, lane=row; vv = v0 + wv + 16*i (guard <500); NT loads
      float best = -INFINITY; int bi = 0x7fffffff;
      for (int ib = 0; ib < 4; ++ib){
        float acc[8];
        #pragma unroll
        for (int jj=0;jj<8;jj++){
          int i = ib*8+jj;
          acc[jj] = (wv + 16*i < 500) ? bout[v0 + wv + 16*i] : 0.f;
        }
        for (int kc = 0; kc < 16; ++kc){
          float x[16];
          #pragma unroll
          for (int u=0;u<16;u++) x[u] = htp[(kc*16+u)*65 + lane];
          #pragma unroll
          for (int jj=0;jj<8;jj++){
            int i = ib*8+jj;
            if (wv + 16*i < 500){
              const float* Wp = Wout + (size_t)(v0 + wv + 16*i)*HID + kc*16;
              #pragma unroll
              for (int u=0;u<16;u++) acc[jj] += __builtin_nontemporal_load(Wp+u)*x[u];
            }
          }
        }
        #pragma unroll
        for (int jj=0;jj<8;jj++){
          int i = ib*8+jj;
          if (wv + 16*i < 500){
            int vv = v0 + wv + 16*i;
            __builtin_nontemporal_store(acc[jj],
                dout + ((size_t)lane*NPRED + t)*VOC + vv);
            if (acc[jj] > best){ best = acc[jj]; bi = vv; }
          }
        }
      }
      xps[wv*64 + lane] = best; iscr[wv*64 + lane] = bi;
      __syncthreads();
      if (wv == 0){
        float bb = xps[lane]; int bbi = iscr[lane];
        #pragma unroll
        for (int w=1; w<16; w++){
          float vl = xps[w*64+lane]; int ii = iscr[w*64+lane];
          if (vl > bb || (vl == bb && ii < bbi)){ bb = vl; bbi = ii; }
        }
        gstoref(pPv + (t&1)*4096 + v*64 + lane, bb);
        gstorei(pPi + (t&1)*4096 + v*64 + lane, bbi);
        asm volatile("s_waitcnt vmcnt(0)" ::: "memory");
      }
      __syncthreads();
      if (tid == 0) gstorei(fP + v, t + 1);
      if (t == NPRED-1) continue;

      // ---- reducer (P0): global argmax (v ascending) + stage emb rows
      if (v == 0){
        if (wv == 0){
          int g = 0;
          while (!__all(gload32(fP + lane) >= t+1) && ++g < (1<<24)) {}
        }
        __syncthreads();
        {
          float bb = -INFINITY; int bbi = 0x7fffffff;
          #pragma unroll
          for (int i=0;i<4;i++){
            int vs = wv*4 + i;
            float vl = gloadf(pPv + (t&1)*4096 + vs*64 + lane);
            int  ii  = gload32(pPi + (t&1)*4096 + vs*64 + lane);
            if (vl > bb || (vl == bb && ii < bbi)){ bb = vl; bbi = ii; }
          }
          xps[wv*64+lane] = bb; iscr[wv*64+lane] = bbi;
        }
        __syncthreads();
        if (wv == 0){
          float bb = xps[lane]; int bbi = iscr[lane];
          #pragma unroll
          for (int w=1; w<16; w++){
            float vl = xps[w*64+lane]; int ii = iscr[w*64+lane];
            if (vl > bb || (vl == bb && ii < bbi)){ bb = vl; bbi = ii; }
          }
          iscr[lane] = bbi;           // token for row = lane
        }
        __syncthreads();
        {
          int tk = iscr[tid & 63];
          int r2 = tid & 63, kb = (tid >> 6) * 16;
          const float* er = emb + (size_t)tk*EMBD + kb;
          #pragma unroll
          for (int i=0;i<16;i++) gstoref(xeG + (kb+i)*64 + r2, er[i]);
          asm volatile("s_waitcnt vmcnt(0)" ::: "memory");
        }
        __syncthreads();
        if (tid == 0) gstorei(fT, t + 1);
      }

      // ---- xproj of position t+1 (all P WGs; j-slice of 16)
      if (tid == 0){
        int g = 0;
        while (gload32(fT) < t + 1 && ++g < (1<<24))
          __builtin_amdgcn_s_sleep(2);
      }
      __syncthreads();
      {
        #pragma unroll
        for (int i=0;i<16;i++){
          int idx = tid + i*1024;               // idx = k*64 + r
          htp[(idx >> 6)*65 + (idx & 63)] = gloadf(xeG + idx);
        }
      }
      __syncthreads();
      {
        int j  = v*16 + jl;
        const float* Wj = Wih0 + (size_t)j*EMBD;
        float acc = b0v;
        #pragma unroll 16
        for (int k=0;k<256;k++) acc += Wj[k]*htp[k*65 + rr];
        // [p][r][j] layout: 16 consecutive floats per rr-group -> coalesced
        gstoref(xp + ((size_t)(t+1)*64 + rr)*G4 + v*16 + jl, acc);
        asm volatile("s_waitcnt vmcnt(0)" ::: "memory");
      }
      __syncthreads();
      if (tid == 0) gstorei(fX + v, t + 1);
    }
  }
}

// -------------------------------- launch ------------------------------------
extern "C" void kernel_launch(void* const* d_in, const int* in_sizes, int n_in,
                              void* d_out, int out_size, void* d_ws, size_t ws_size,
                              hipStream_t stream)
{
  const int*   input_seq  = (const int*)d_in[0];
  const int*   target_seq = (const int*)d_in[1];
  const float* enc_emb = (const float*)d_in[2];
  const float* dec_emb = (const float*)d_in[3];
  const float* enc_Wih = (const float*)d_in[4];
  const float* enc_Whh = (const float*)d_in[5];
  const float* enc_b   = (const float*)d_in[6];
  const float* dec_Wih = (const float*)d_in[7];
  const float* dec_Whh = (const float*)d_in[8];
  const float* dec_b   = (const float*)d_in[9];
  const float* W_out   = (const float*)d_in[10];
  const float* b_out   = (const float*)d_in[11];
  float* out = (float*)d_out;

  float* ws   = (float*)d_ws;
  float* xp_e = ws;                               // 64*64*1024
  float* xp_d = xp_e + (size_t)SLEN*64*G4;        // 32*64*1024
  float* h0P  = xp_d + (size_t)TLEN*64*G4;        // 256*64
  float* h1P  = h0P + HID*64;
  float* c0P  = h1P + HID*64;
  float* c1P  = c0P + HID*64;
  float* h0R  = c1P + HID*64;                     // 4*16384
  float* p1R  = h0R + 4*16384;                    // 4*65536
  float* h1R  = p1R + 4*65536;                    // 2*16384
  float* pPv  = h1R + 2*16384;                    // 2*4096
  int*   pPi  = (int*)(pPv + 2*4096);             // 2*4096
  float* xeG  = (float*)(pPi + 2*4096);           // 16384
  int*   flags= (int*)(xeG + 16384);              // 512
  float* WT0  = (float*)(flags + 512);            // 3 * 256*1024
  float* WT1i = WT0  + HID*G4;
  float* WT1h = WT1i + HID*G4;

  k_zero<<<1, 512, 0, stream>>>(flags);

  dim3 trg(16, 4);
  // encoder
  k_tr<<<trg, 256, 0, stream>>>(enc_Whh,                   WT0);
  k_tr<<<trg, 256, 0, stream>>>(enc_Wih + (size_t)G4*EMBD, WT1i);
  k_tr<<<trg, 256, 0, stream>>>(enc_Whh + (size_t)G4*HID,  WT1h);
  k_xproj<<<dim3(32, SLEN), 256, 0, stream>>>(input_seq, SLEN, 0, enc_emb,
        enc_Wih, enc_b, xp_e);
  k_pipe<<<192, 1024, 0, stream>>>(xp_e, SLEN,
        WT0, WT1i, WT1h, enc_b + G4,
        h0P, h1P, c0P, c1P, h0R, p1R,
        flags, flags + 64, flags + 128, 0, 1);

  // decoder weights + BOS xproj (position 0)
  k_tr<<<trg, 256, 0, stream>>>(dec_Whh,                   WT0);
  k_tr<<<trg, 256, 0, stream>>>(dec_Wih + (size_t)G4*EMBD, WT1i);
  k_tr<<<trg, 256, 0, stream>>>(dec_Whh + (size_t)G4*HID,  WT1h);
  k_xproj<<<dim3(32, 1), 256, 0, stream>>>(target_seq, TLEN, 0, dec_emb,
        dec_Wih, dec_b, xp_d);

  // persistent decoder
  k_megadec<<<256, 1024, 0, stream>>>(xp_d,
        WT0, WT1i, WT1h, dec_b + G4,
        dec_Wih, dec_b, dec_emb, W_out, b_out, out,
        h0P, h1P, c0P, c1P,
        h0R, p1R, h1R, pPv, pPi, xeG, flags);
}

// Round 13
// 9318.449 us; speedup vs baseline: 1.1156x; 1.1156x over previous
//
#include <hip/hip_runtime.h>
#include <math.h>

// ---------------------------------------------------------------------------
// Seq2SeqLSTM on MI355X -- Round 12: R11 minus the NT-store mistake.
//
// R11 evidence: xp [p][r][j] fix worked (FETCH 2.27->1.49GB) but NT dout
// stores bypassed L2 -> 16x write amplification (WRITE 0.46->4.0GB, +1.7ms).
// R12: cached dout stores (R10 path, 463MB), keep NT loads for Wout only,
// keep xp layout + sc1-first-touch-only reads. Choreography unchanged.
// ---------------------------------------------------------------------------

#define B     64
#define SLEN  64
#define TLEN  32
#define HID   256
#define EMBD  256
#define G4    1024
#define VOC   32000
#define NPRED 31
#define FBASE 64        // flag value after encoder (64 positions)

typedef unsigned long long u64;

__device__ __forceinline__ float sigf(float x){ return 1.0f/(1.0f+__expf(-x)); }

__device__ __forceinline__ void gstoref(float* p, float v){
  __hip_atomic_store(p, v, __ATOMIC_RELAXED, __HIP_MEMORY_SCOPE_AGENT);
}
__device__ __forceinline__ void gstorei(int* p, int v){
  __hip_atomic_store(p, v, __ATOMIC_RELAXED, __HIP_MEMORY_SCOPE_AGENT);
}
__device__ __forceinline__ float gloadf(const float* p){
  return __hip_atomic_load(p, __ATOMIC_RELAXED, __HIP_MEMORY_SCOPE_AGENT);
}
__device__ __forceinline__ int gload32(const int* p){
  return __hip_atomic_load(p, __ATOMIC_RELAXED, __HIP_MEMORY_SCOPE_AGENT);
}

// --------------------------------- zero ------------------------------------
__global__ void k_zero(int* __restrict__ p){
  p[threadIdx.x] = 0;    // block 512
}

// ------------------------------- transpose ----------------------------------
__global__ __launch_bounds__(256) void k_tr(const float* __restrict__ src,
                                            float* __restrict__ dst){
  __shared__ float t[64][65];
  const int r0 = blockIdx.x*64, c0 = blockIdx.y*64;
  const int lr = threadIdx.x>>6, lc = threadIdx.x&63;
  #pragma unroll
  for (int i=0;i<16;i++){
    int r = lr + i*4;
    t[r][lc] = src[(size_t)(r0+r)*256 + c0+lc];
  }
  __syncthreads();
  #pragma unroll
  for (int i=0;i<16;i++){
    int c = lr + i*4;
    dst[(size_t)(c0+c)*1024 + r0+lc] = t[lc][c];
  }
}

// --------------------------------- xproj -----------------------------------
// layout: out[(pos*64 + r)*G4 + j]
__global__ __launch_bounds__(256) void k_xproj(
    const int* __restrict__ tok, int tok_stride, int pos0,
    const float* __restrict__ emb, const float* __restrict__ W,
    const float* __restrict__ b0, float* __restrict__ out)
{
  __shared__ float xT[128][64];
  const int tid  = threadIdx.x;
  const int lane = tid & 63;
  const int wv   = __builtin_amdgcn_readfirstlane(tid >> 6);
  const int pos  = pos0 + blockIdx.y;
  const int jbase= blockIdx.x*32 + wv*8;

  const int rS = tid >> 2, klane = tid & 3;
  const int tokrow = tok[rS*tok_stride + pos];
  const float* xsrc = emb + (size_t)tokrow*EMBD;

  float acc[8];
  #pragma unroll
  for (int jj=0;jj<8;jj++) acc[jj]=0.f;

  for (int c=0;c<2;c++){
    __syncthreads();
    #pragma unroll
    for (int i=0;i<32;i++){
      int k = klane + 4*i;
      xT[k][rS] = xsrc[c*128 + k];
    }
    __syncthreads();
    for (int kc=0;kc<8;kc++){
      float x[16];
      #pragma unroll
      for (int i=0;i<16;i++) x[i] = xT[kc*16+i][lane];
      #pragma unroll
      for (int jj=0;jj<8;jj++){
        const float* Wp = W + (size_t)(jbase+jj)*EMBD + c*128 + kc*16;
        float s = 0.f;
        #pragma unroll
        for (int i=0;i<16;i++) s += Wp[i]*x[i];
        acc[jj] += s;
      }
    }
  }
  #pragma unroll
  for (int jj=0;jj<8;jj++){
    int j = jbase+jj;
    out[((size_t)pos*64 + lane)*G4 + j] = acc[jj] + b0[j];
  }
}

// ------------------------------- dotpart ------------------------------------
__device__ __forceinline__ float4 dotpart(const float4* __restrict__ Wq,
                                          const float* __restrict__ hs,
                                          int kq, int jg){
  float ax=0.f, ay=0.f, az=0.f, aw=0.f;
  const float4* __restrict__ hq = (const float4*)(hs + (kq<<6));
  const float4* __restrict__ w  = Wq + (size_t)(kq<<6)*256 + jg;
  #pragma unroll 4
  for (int kk=0; kk<16; ++kk){
    float4 h4 = hq[kk];
    float4 w0 = w[0];
    float4 w1 = w[256];
    float4 w2 = w[512];
    float4 w3 = w[768];
    ax += w0.x*h4.x; ay += w0.y*h4.x; az += w0.z*h4.x; aw += w0.w*h4.x;
    ax += w1.x*h4.y; ay += w1.y*h4.y; az += w1.z*h4.y; aw += w1.w*h4.y;
    ax += w2.x*h4.z; ay += w2.y*h4.z; az += w2.z*h4.z; aw += w2.w*h4.z;
    ax += w3.x*h4.w; ay += w3.y*h4.w; az += w3.z*h4.w; aw += w3.w*h4.w;
    w += 1024;
  }
  return make_float4(ax,ay,az,aw);
}

// --------------------------- encoder pipe (R8) -------------------------------
__global__ __launch_bounds__(1024) void k_pipe(
    const float* __restrict__ xp, int nsteps,
    const float* __restrict__ WT0, const float* __restrict__ WT1i,
    const float* __restrict__ WT1h, const float* __restrict__ b1,
    float* __restrict__ h0P, float* __restrict__ h1P,
    float* __restrict__ c0P, float* __restrict__ c1P,
    float* __restrict__ h0R, float* __restrict__ p1R,
    int* __restrict__ fA, int* __restrict__ fB1, int* __restrict__ fB2,
    int fbase, int initzero)
{
  __shared__ __align__(16) float part[4][4096];
  __shared__ float xps[1024];
  __shared__ __align__(16) float hloc[256];
  __shared__ float padL[4096];
  const int tid  = threadIdx.x;
  const int kq   = tid >> 8, jg = tid & 255;
  const int role = blockIdx.x >> 6;
  const int r    = blockIdx.x & 63;
  if (nsteps < 0){ padL[tid] = xp[tid]; h0R[tid] = padL[tid ^ 1]; }

  if (role == 0){
    float c0 = 0.f;
    if (tid < HID){
      if (initzero){ c0 = 0.f; hloc[tid] = 0.f; }
      else { c0 = c0P[tid*64 + r]; hloc[tid] = h0P[tid*64 + r]; }
    }
    __syncthreads();
    const float4* W4 = (const float4*)WT0;
    for (int q = 0; q < nsteps; ++q){
      float xv = xp[((size_t)q*64 + r)*G4 + tid];   // coalesced 4KB
      if (tid == 0 && q >= 4){
        int tgt = fbase + q - 3, g = 0;
        while (gload32(fB1 + r) < tgt && ++g < (1<<24)) {}
      }
      float4 a = dotpart(W4, hloc, kq, jg);
      xps[tid] = xv;
      *(float4*)&part[kq][jg<<2] = a;
      __syncthreads();
      if (tid < HID){
        float g0 = part[0][tid]+part[1][tid]+part[2][tid]+part[3][tid] + xps[tid];
        float g1 = part[0][HID+tid]+part[1][HID+tid]+part[2][HID+tid]+part[3][HID+tid] + xps[HID+tid];
        float g2 = part[0][2*HID+tid]+part[1][2*HID+tid]+part[2][2*HID+tid]+part[3][2*HID+tid] + xps[2*HID+tid];
        float g3 = part[0][3*HID+tid]+part[1][3*HID+tid]+part[2][3*HID+tid]+part[3][3*HID+tid] + xps[3*HID+tid];
        c0 = sigf(g1)*c0 + sigf(g0)*tanhf(g2);
        float h = sigf(g3)*tanhf(c0);
        hloc[tid] = h;
        gstoref(h0R + (q&3)*16384 + r*256 + tid, h);
        asm volatile("s_waitcnt vmcnt(0)" ::: "memory");
      }
      __syncthreads();
      if (tid == 0) gstorei(fA + r, fbase + q + 1);
    }
    if (tid < HID){ c0P[tid*64 + r] = c0; h0P[tid*64 + r] = hloc[tid]; }
  }
  else if (role == 1){
    const float4* W4 = (const float4*)WT1i;
    for (int q = 0; q < nsteps; ++q){
      if (tid == 0){
        int tgt = fbase + q + 1, g = 0;
        while (gload32(fA + r) < tgt && ++g < (1<<24)) {}
        if (q >= 4){
          int t2 = fbase + q - 3; g = 0;
          while (gload32(fB2 + r) < t2 && ++g < (1<<24)) {}
        }
      }
      __syncthreads();
      if (tid < HID) hloc[tid] = gloadf(h0R + (q&3)*16384 + r*256 + tid);
      __syncthreads();
      float4 a = dotpart(W4, hloc, kq, jg);
      *(float4*)&part[kq][jg<<2] = a;
      __syncthreads();
      float p = part[0][tid]+part[1][tid]+part[2][tid]+part[3][tid];
      gstoref(p1R + (q&3)*65536 + r*1024 + tid, p);
      asm volatile("s_waitcnt vmcnt(0)" ::: "memory");
      __syncthreads();
      if (tid == 0) gstorei(fB1 + r, fbase + q + 1);
    }
  }
  else {
    float c1 = 0.f, bb0=0.f, bb1=0.f, bb2=0.f, bb3=0.f;
    if (tid < HID){
      bb0 = b1[tid]; bb1 = b1[HID+tid]; bb2 = b1[2*HID+tid]; bb3 = b1[3*HID+tid];
      if (initzero){ c1 = 0.f; hloc[tid] = 0.f; }
      else { c1 = c1P[tid*64 + r]; hloc[tid] = h1P[tid*64 + r]; }
    }
    __syncthreads();
    const float4* W4 = (const float4*)WT1h;
    for (int q = 0; q < nsteps; ++q){
      if (tid == 0){
        int tgt = fbase + q + 1, g = 0;
        while (gload32(fB1 + r) < tgt && ++g < (1<<24)) {}
      }
      __syncthreads();
      xps[tid] = gloadf(p1R + (q&3)*65536 + r*1024 + tid);
      asm volatile("s_waitcnt vmcnt(0)" ::: "memory");
      __syncthreads();
      if (tid == 0) gstorei(fB2 + r, fbase + q + 1);
      float4 a = dotpart(W4, hloc, kq, jg);
      *(float4*)&part[kq][jg<<2] = a;
      __syncthreads();
      if (tid < HID){
        float g0 = part[0][tid]+part[1][tid]+part[2][tid]+part[3][tid] + xps[tid] + bb0;
        float g1 = part[0][HID+tid]+part[1][HID+tid]+part[2][HID+tid]+part[3][HID+tid] + xps[HID+tid] + bb1;
        float g2 = part[0][2*HID+tid]+part[1][2*HID+tid]+part[2][2*HID+tid]+part[3][2*HID+tid] + xps[2*HID+tid] + bb2;
        float g3 = part[0][3*HID+tid]+part[1][3*HID+tid]+part[2][3*HID+tid]+part[3][3*HID+tid] + xps[3*HID+tid] + bb3;
        c1 = sigf(g1)*c1 + sigf(g0)*tanhf(g2);
        float h = sigf(g3)*tanhf(c1);
        hloc[tid] = h;
        if (q == nsteps-1) h1P[tid*64 + r] = h;
      }
      __syncthreads();
    }
    if (tid < HID) c1P[tid*64 + r] = c1;
  }
}

// ------------------------- persistent decoder --------------------------------
// flags: fA[0..63] fB1[64..127] fB2[128..191] fH[192..255] fP[256..319]
//        fX[320..383] fT[384]
__global__ __launch_bounds__(1024) void k_megadec(
    float* xp,                             // xp_d [32][64][1024] (RW)
    const float* __restrict__ WT0, const float* __restrict__ WT1i,
    const float* __restrict__ WT1h, const float* __restrict__ b1,
    const float* __restrict__ Wih0, const float* __restrict__ b0,
    const float* __restrict__ emb,
    const float* __restrict__ Wout, const float* __restrict__ bout,
    float* __restrict__ dout,
    const float* __restrict__ h0P, const float* __restrict__ h1P,
    const float* __restrict__ c0P, const float* __restrict__ c1P,
    float* __restrict__ h0R, float* __restrict__ p1R, float* __restrict__ h1R,
    float* __restrict__ pPv, int* __restrict__ pPi, float* __restrict__ xeG,
    int* __restrict__ flags)
{
  __shared__ __align__(16) float part[4][4096];   // 64 KB
  __shared__ float xps[1024];                     //  4 KB
  __shared__ __align__(16) float hloc[256];       //  1 KB
  __shared__ int   iscr[1024];                    //  4 KB
  __shared__ float htp[256*65];                   // 65 KB (padded [k][r])

  int* fA = flags;        int* fB1 = flags + 64;  int* fB2 = flags + 128;
  int* fH = flags + 192;  int* fP  = flags + 256; int* fX  = flags + 320;
  int* fT = flags + 384;

  const int tid  = threadIdx.x;
  const int lane = tid & 63;
  const int wv   = __builtin_amdgcn_readfirstlane(tid >> 6);
  const int kq   = tid >> 8, jg = tid & 255;
  const int role = blockIdx.x >> 6;
  const int r    = blockIdx.x & 63;

  // =========================== role A: layer 0 =============================
  if (role == 0){
    float c0 = 0.f;
    if (tid < HID){ c0 = c0P[tid*64 + r]; hloc[tid] = h0P[tid*64 + r]; }
    __syncthreads();
    const float4* W4 = (const float4*)WT0;
    int cum = 0;
    for (int t = 0; t < NPRED; ++t)
    for (int p = 0; p <= t; ++p, ++cum){
      if (wv == 0){
        if (lane == 0 && cum >= 4){
          int tgt = FBASE + cum - 3, g = 0;
          while (gload32(fB1 + r) < tgt && ++g < (1<<24)) {}
        }
        if (p == t && t >= 1){
          int g = 0;
          while (!__all(gload32(fX + lane) >= t) && ++g < (1<<24)) {}
        }
      }
      __syncthreads();
      const float* xa = xp + ((size_t)p*64 + r)*G4 + tid;   // coalesced
      float xv = (p == t) ? gloadf(xa) : *xa;   // sc1 first touch only
      float4 a = dotpart(W4, hloc, kq, jg);
      xps[tid] = xv;
      *(float4*)&part[kq][jg<<2] = a;
      __syncthreads();
      if (tid < HID){
        float g0 = part[0][tid]+part[1][tid]+part[2][tid]+part[3][tid] + xps[tid];
        float g1 = part[0][HID+tid]+part[1][HID+tid]+part[2][HID+tid]+part[3][HID+tid] + xps[HID+tid];
        float g2 = part[0][2*HID+tid]+part[1][2*HID+tid]+part[2][2*HID+tid]+part[3][2*HID+tid] + xps[2*HID+tid];
        float g3 = part[0][3*HID+tid]+part[1][3*HID+tid]+part[2][3*HID+tid]+part[3][3*HID+tid] + xps[3*HID+tid];
        c0 = sigf(g1)*c0 + sigf(g0)*tanhf(g2);
        float h = sigf(g3)*tanhf(c0);
        hloc[tid] = h;
        gstoref(h0R + (cum&3)*16384 + r*256 + tid, h);
        asm volatile("s_waitcnt vmcnt(0)" ::: "memory");
      }
      __syncthreads();
      if (tid == 0) gstorei(fA + r, FBASE + cum + 1);
    }
  }
  // =========================== role B1: Wih1.h0 ============================
  else if (role == 1){
    const float4* W4 = (const float4*)WT1i;
    int cum = 0;
    for (int t = 0; t < NPRED; ++t)
    for (int p = 0; p <= t; ++p, ++cum){
      if (tid == 0){
        int tgt = FBASE + cum + 1, g = 0;
        while (gload32(fA + r) < tgt && ++g < (1<<24)) {}
        if (cum >= 4){
          int t2 = FBASE + cum - 3; g = 0;
          while (gload32(fB2 + r) < t2 && ++g < (1<<24)) {}
        }
      }
      __syncthreads();
      if (tid < HID) hloc[tid] = gloadf(h0R + (cum&3)*16384 + r*256 + tid);
      __syncthreads();
      float4 a = dotpart(W4, hloc, kq, jg);
      *(float4*)&part[kq][jg<<2] = a;
      __syncthreads();
      float pp = part[0][tid]+part[1][tid]+part[2][tid]+part[3][tid];
      gstoref(p1R + (cum&3)*65536 + r*1024 + tid, pp);
      asm volatile("s_waitcnt vmcnt(0)" ::: "memory");
      __syncthreads();
      if (tid == 0) gstorei(fB1 + r, FBASE + cum + 1);
    }
  }
  // ================== role B2: Whh1.h1 + combine + act =====================
  else if (role == 2){
    float c1 = 0.f, bb0=0.f, bb1=0.f, bb2=0.f, bb3=0.f;
    if (tid < HID){
      bb0 = b1[tid]; bb1 = b1[HID+tid]; bb2 = b1[2*HID+tid]; bb3 = b1[3*HID+tid];
      c1 = c1P[tid*64 + r]; hloc[tid] = h1P[tid*64 + r];
    }
    __syncthreads();
    const float4* W4 = (const float4*)WT1h;
    int cum = 0;
    for (int t = 0; t < NPRED; ++t)
    for (int p = 0; p <= t; ++p, ++cum){
      if (tid == 0){
        int tgt = FBASE + cum + 1, g = 0;
        while (gload32(fB1 + r) < tgt && ++g < (1<<24)) {}
      }
      __syncthreads();
      xps[tid] = gloadf(p1R + (cum&3)*65536 + r*1024 + tid);
      asm volatile("s_waitcnt vmcnt(0)" ::: "memory");
      __syncthreads();
      if (tid == 0) gstorei(fB2 + r, FBASE + cum + 1);
      float4 a = dotpart(W4, hloc, kq, jg);
      *(float4*)&part[kq][jg<<2] = a;
      __syncthreads();
      if (tid < HID){
        float g0 = part[0][tid]+part[1][tid]+part[2][tid]+part[3][tid] + xps[tid] + bb0;
        float g1 = part[0][HID+tid]+part[1][HID+tid]+part[2][HID+tid]+part[3][HID+tid] + xps[HID+tid] + bb1;
        float g2 = part[0][2*HID+tid]+part[1][2*HID+tid]+part[2][2*HID+tid]+part[3][2*HID+tid] + xps[2*HID+tid] + bb2;
        float g3 = part[0][3*HID+tid]+part[1][3*HID+tid]+part[2][3*HID+tid]+part[3][3*HID+tid] + xps[3*HID+tid] + bb3;
        c1 = sigf(g1)*c1 + sigf(g0)*tanhf(g2);
        float h = sigf(g3)*tanhf(c1);
        hloc[tid] = h;
      }
      __syncthreads();
      if (p == t){
        if (tid == 0 && t >= 2){
          int g = 0;
          while (gload32(fT) < t - 1 && ++g < (1<<24)) {}
        }
        __syncthreads();
        if (tid < HID){
          gstoref(h1R + (t&1)*16384 + r*256 + tid, hloc[tid]);   // [r][k]
          asm volatile("s_waitcnt vmcnt(0)" ::: "memory");
        }
        __syncthreads();
        if (tid == 0) gstorei(fH + r, t + 1);
      }
    }
  }
  // ================== role P: pred + argmax + xproj ========================
  else {
    const int v  = r;                 // vocab slice id 0..63
    const int v0 = v * 500;
    const int rr = tid >> 4;          // 0..63  (row, for xproj)
    const int jl = tid & 15;          // 0..15  (j within slice)
    const float b0v = b0[v*16 + jl];

    for (int t = 0; t < NPRED; ++t){
      if (wv == 0){
        int g = 0;
        while (!__all(gload32(fH + lane) >= t+1) && ++g < (1<<24))
          __builtin_amdgcn_s_sleep(4);
      }
      if (tid == 0 && t >= 2){
        int g = 0;
        while (gload32(fT) < t - 1 && ++g < (1<<24)) {}
      }
      __syncthreads();
      // stage h1R[t&1] ([r][k]) -> htp[k*65+r]
      {
        const float* src = h1R + (size_t)(t&1)*16384;
        #pragma unroll
        for (int i=0;i<16;i++){
          int idx = tid + i*1024;
          float vl = gloadf(src + idx);
          htp[(idx & 255)*65 + (idx >> 8)] = vl;
        }
      }
      __syncthreads();
      // pred: wave wv, lane=row; vv = v0 + wv + 16*i (guard <500); NT Wout loads
      float best = -INFINITY; int bi = 0x7fffffff;
      for (int ib = 0; ib < 4; ++ib){
        float acc[8];
        #pragma unroll
        for (int jj=0;jj<8;jj++){
          int i = ib*8+jj;
          acc[jj] = (wv + 16*i < 500) ? bout[v0 + wv + 16*i] : 0.f;
        }
        for (int kc = 0; kc < 16; ++kc){
          float x[16];
          #pragma unroll
          for (int u=0;u<16;u++) x[u] = htp[(kc*16+u)*65 + lane];
          #pragma unroll
          for (int jj=0;jj<8;jj++){
            int i = ib*8+jj;
            if (wv + 16*i < 500){
              const float* Wp = Wout + (size_t)(v0 + wv + 16*i)*HID + kc*16;
              #pragma unroll
              for (int u=0;u<16;u++) acc[jj] += __builtin_nontemporal_load(Wp+u)*x[u];
            }
          }
        }
        #pragma unroll
        for (int jj=0;jj<8;jj++){
          int i = ib*8+jj;
          if (wv + 16*i < 500){
            int vv = v0 + wv + 16*i;
            dout[((size_t)lane*NPRED + t)*VOC + vv] = acc[jj];   // cached store
            if (acc[jj] > best){ best = acc[jj]; bi = vv; }
          }
        }
      }
      xps[wv*64 + lane] = best; iscr[wv*64 + lane] = bi;
      __syncthreads();
      if (wv == 0){
        float bb = xps[lane]; int bbi = iscr[lane];
        #pragma unroll
        for (int w=1; w<16; w++){
          float vl = xps[w*64+lane]; int ii = iscr[w*64+lane];
          if (vl > bb || (vl == bb && ii < bbi)){ bb = vl; bbi = ii; }
        }
        gstoref(pPv + (t&1)*4096 + v*64 + lane, bb);
        gstorei(pPi + (t&1)*4096 + v*64 + lane, bbi);
        asm volatile("s_waitcnt vmcnt(0)" ::: "memory");
      }
      __syncthreads();
      if (tid == 0) gstorei(fP + v, t + 1);
      if (t == NPRED-1) continue;

      // ---- reducer (P0): global argmax (v ascending) + stage emb rows
      if (v == 0){
        if (wv == 0){
          int g = 0;
          while (!__all(gload32(fP + lane) >= t+1) && ++g < (1<<24)) {}
        }
        __syncthreads();
        {
          float bb = -INFINITY; int bbi = 0x7fffffff;
          #pragma unroll
          for (int i=0;i<4;i++){
            int vs = wv*4 + i;
            float vl = gloadf(pPv + (t&1)*4096 + vs*64 + lane);
            int  ii  = gload32(pPi + (t&1)*4096 + vs*64 + lane);
            if (vl > bb || (vl == bb && ii < bbi)){ bb = vl; bbi = ii; }
          }
          xps[wv*64+lane] = bb; iscr[wv*64+lane] = bbi;
        }
        __syncthreads();
        if (wv == 0){
          float bb = xps[lane]; int bbi = iscr[lane];
          #pragma unroll
          for (int w=1; w<16; w++){
            float vl = xps[w*64+lane]; int ii = iscr[w*64+lane];
            if (vl > bb || (vl == bb && ii < bbi)){ bb = vl; bbi = ii; }
          }
          iscr[lane] = bbi;           // token for row = lane
        }
        __syncthreads();
        {
          int tk = iscr[tid & 63];
          int r2 = tid & 63, kb = (tid >> 6) * 16;
          const float* er = emb + (size_t)tk*EMBD + kb;
          #pragma unroll
          for (int i=0;i<16;i++) gstoref(xeG + (kb+i)*64 + r2, er[i]);
          asm volatile("s_waitcnt vmcnt(0)" ::: "memory");
        }
        __syncthreads();
        if (tid == 0) gstorei(fT, t + 1);
      }

      // ---- xproj of position t+1 (all P WGs; j-slice of 16)
      if (tid == 0){
        int g = 0;
        while (gload32(fT) < t + 1 && ++g < (1<<24))
          __builtin_amdgcn_s_sleep(2);
      }
      __syncthreads();
      {
        #pragma unroll
        for (int i=0;i<16;i++){
          int idx = tid + i*1024;               // idx = k*64 + r
          htp[(idx >> 6)*65 + (idx & 63)] = gloadf(xeG + idx);
        }
      }
      __syncthreads();
      {
        int j  = v*16 + jl;
        const float* Wj = Wih0 + (size_t)j*EMBD;
        float acc = b0v;
        #pragma unroll 16
        for (int k=0;k<256;k++) acc += Wj[k]*htp[k*65 + rr];
        gstoref(xp + ((size_t)(t+1)*64 + rr)*G4 + v*16 + jl, acc);
        asm volatile("s_waitcnt vmcnt(0)" ::: "memory");
      }
      __syncthreads();
      if (tid == 0) gstorei(fX + v, t + 1);
    }
  }
}

// -------------------------------- launch ------------------------------------
extern "C" void kernel_launch(void* const* d_in, const int* in_sizes, int n_in,
                              void* d_out, int out_size, void* d_ws, size_t ws_size,
                              hipStream_t stream)
{
  const int*   input_seq  = (const int*)d_in[0];
  const int*   target_seq = (const int*)d_in[1];
  const float* enc_emb = (const float*)d_in[2];
  const float* dec_emb = (const float*)d_in[3];
  const float* enc_Wih = (const float*)d_in[4];
  const float* enc_Whh = (const float*)d_in[5];
  const float* enc_b   = (const float*)d_in[6];
  const float* dec_Wih = (const float*)d_in[7];
  const float* dec_Whh = (const float*)d_in[8];
  const float* dec_b   = (const float*)d_in[9];
  const float* W_out   = (const float*)d_in[10];
  const float* b_out   = (const float*)d_in[11];
  float* out = (float*)d_out;

  float* ws   = (float*)d_ws;
  float* xp_e = ws;                               // 64*64*1024
  float* xp_d = xp_e + (size_t)SLEN*64*G4;        // 32*64*1024
  float* h0P  = xp_d + (size_t)TLEN*64*G4;        // 256*64
  float* h1P  = h0P + HID*64;
  float* c0P  = h1P + HID*64;
  float* c1P  = c0P + HID*64;
  float* h0R  = c1P + HID*64;                     // 4*16384
  float* p1R  = h0R + 4*16384;                    // 4*65536
  float* h1R  = p1R + 4*65536;                    // 2*16384
  float* pPv  = h1R + 2*16384;                    // 2*4096
  int*   pPi  = (int*)(pPv + 2*4096);             // 2*4096
  float* xeG  = (float*)(pPi + 2*4096);           // 16384
  int*   flags= (int*)(xeG + 16384);              // 512
  float* WT0  = (float*)(flags + 512);            // 3 * 256*1024
  float* WT1i = WT0  + HID*G4;
  float* WT1h = WT1i + HID*G4;

  k_zero<<<1, 512, 0, stream>>>(flags);

  dim3 trg(16, 4);
  // encoder
  k_tr<<<trg, 256, 0, stream>>>(enc_Whh,                   WT0);
  k_tr<<<trg, 256, 0, stream>>>(enc_Wih + (size_t)G4*EMBD, WT1i);
  k_tr<<<trg, 256, 0, stream>>>(enc_Whh + (size_t)G4*HID,  WT1h);
  k_xproj<<<dim3(32, SLEN), 256, 0, stream>>>(input_seq, SLEN, 0, enc_emb,
        enc_Wih, enc_b, xp_e);
  k_pipe<<<192, 1024, 0, stream>>>(xp_e, SLEN,
        WT0, WT1i, WT1h, enc_b + G4,
        h0P, h1P, c0P, c1P, h0R, p1R,
        flags, flags + 64, flags + 128, 0, 1);

  // decoder weights + BOS xproj (position 0)
  k_tr<<<trg, 256, 0, stream>>>(dec_Whh,                   WT0);
  k_tr<<<trg, 256, 0, stream>>>(dec_Wih + (size_t)G4*EMBD, WT1i);
  k_tr<<<trg, 256, 0, stream>>>(dec_Whh + (size_t)G4*HID,  WT1h);
  k_xproj<<<dim3(32, 1), 256, 0, stream>>>(target_seq, TLEN, 0, dec_emb,
        dec_Wih, dec_b, xp_d);

  // persistent decoder
  k_megadec<<<256, 1024, 0, stream>>>(xp_d,
        WT0, WT1i, WT1h, dec_b + G4,
        dec_Wih, dec_b, dec_emb, W_out, b_out, out,
        h0P, h1P, c0P, c1P,
        h0R, p1R, h1R, pPv, pPi, xeG, flags);
}

// Round 14
// 8880.819 us; speedup vs baseline: 1.1706x; 1.0493x over previous
//
#include <hip/hip_runtime.h>
#include <math.h>

// ---------------------------------------------------------------------------
// Seq2SeqLSTM on MI355X -- Round 13: XCD-partitioned roles + L2-resident Wout.
//
// R12 decomposition: megadec 8.8ms = 5.4ms A-chain floor (496 x 10.9us) +
// ~3.4ms boundary stalls (~110us/t exposed pred). FETCH 1.6GB ~= 1.0GB of NT
// Wout re-streamed from HBM every t (NT never caches); P traffic shared every
// XCD with the chain. R13 (k_megadec only):
//  1) role<->XCD partition: xcd=bid&7, role=xcd>>1, r=(xcd&1)*32+(bid>>3).
//     A=XCD0-1, B1=2-3, B2=4-5, P=6-7. Chain L2s hold only their 1MB weight
//     matrix; P's streaming isolated to XCDs 6-7.
//  2) cached Wout loads (drop NT): 8 P WGs/XCD x 512KB = 4MB = L2 capacity,
//     dedicated -> near-resident across t; pred ~100us -> ~10-30us.
// Everything else identical to R12 (choreography proven 3x).
// ---------------------------------------------------------------------------

#define B     64
#define SLEN  64
#define TLEN  32
#define HID   256
#define EMBD  256
#define G4    1024
#define VOC   32000
#define NPRED 31
#define FBASE 64        // flag value after encoder (64 positions)

typedef unsigned long long u64;

__device__ __forceinline__ float sigf(float x){ return 1.0f/(1.0f+__expf(-x)); }

__device__ __forceinline__ void gstoref(float* p, float v){
  __hip_atomic_store(p, v, __ATOMIC_RELAXED, __HIP_MEMORY_SCOPE_AGENT);
}
__device__ __forceinline__ void gstorei(int* p, int v){
  __hip_atomic_store(p, v, __ATOMIC_RELAXED, __HIP_MEMORY_SCOPE_AGENT);
}
__device__ __forceinline__ float gloadf(const float* p){
  return __hip_atomic_load(p, __ATOMIC_RELAXED, __HIP_MEMORY_SCOPE_AGENT);
}
__device__ __forceinline__ int gload32(const int* p){
  return __hip_atomic_load(p, __ATOMIC_RELAXED, __HIP_MEMORY_SCOPE_AGENT);
}

// --------------------------------- zero ------------------------------------
__global__ void k_zero(int* __restrict__ p){
  p[threadIdx.x] = 0;    // block 512
}

// ------------------------------- transpose ----------------------------------
__global__ __launch_bounds__(256) void k_tr(const float* __restrict__ src,
                                            float* __restrict__ dst){
  __shared__ float t[64][65];
  const int r0 = blockIdx.x*64, c0 = blockIdx.y*64;
  const int lr = threadIdx.x>>6, lc = threadIdx.x&63;
  #pragma unroll
  for (int i=0;i<16;i++){
    int r = lr + i*4;
    t[r][lc] = src[(size_t)(r0+r)*256 + c0+lc];
  }
  __syncthreads();
  #pragma unroll
  for (int i=0;i<16;i++){
    int c = lr + i*4;
    dst[(size_t)(c0+c)*1024 + r0+lc] = t[lc][c];
  }
}

// --------------------------------- xproj -----------------------------------
// layout: out[(pos*64 + r)*G4 + j]
__global__ __launch_bounds__(256) void k_xproj(
    const int* __restrict__ tok, int tok_stride, int pos0,
    const float* __restrict__ emb, const float* __restrict__ W,
    const float* __restrict__ b0, float* __restrict__ out)
{
  __shared__ float xT[128][64];
  const int tid  = threadIdx.x;
  const int lane = tid & 63;
  const int wv   = __builtin_amdgcn_readfirstlane(tid >> 6);
  const int pos  = pos0 + blockIdx.y;
  const int jbase= blockIdx.x*32 + wv*8;

  const int rS = tid >> 2, klane = tid & 3;
  const int tokrow = tok[rS*tok_stride + pos];
  const float* xsrc = emb + (size_t)tokrow*EMBD;

  float acc[8];
  #pragma unroll
  for (int jj=0;jj<8;jj++) acc[jj]=0.f;

  for (int c=0;c<2;c++){
    __syncthreads();
    #pragma unroll
    for (int i=0;i<32;i++){
      int k = klane + 4*i;
      xT[k][rS] = xsrc[c*128 + k];
    }
    __syncthreads();
    for (int kc=0;kc<8;kc++){
      float x[16];
      #pragma unroll
      for (int i=0;i<16;i++) x[i] = xT[kc*16+i][lane];
      #pragma unroll
      for (int jj=0;jj<8;jj++){
        const float* Wp = W + (size_t)(jbase+jj)*EMBD + c*128 + kc*16;
        float s = 0.f;
        #pragma unroll
        for (int i=0;i<16;i++) s += Wp[i]*x[i];
        acc[jj] += s;
      }
    }
  }
  #pragma unroll
  for (int jj=0;jj<8;jj++){
    int j = jbase+jj;
    out[((size_t)pos*64 + lane)*G4 + j] = acc[jj] + b0[j];
  }
}

// ------------------------------- dotpart ------------------------------------
__device__ __forceinline__ float4 dotpart(const float4* __restrict__ Wq,
                                          const float* __restrict__ hs,
                                          int kq, int jg){
  float ax=0.f, ay=0.f, az=0.f, aw=0.f;
  const float4* __restrict__ hq = (const float4*)(hs + (kq<<6));
  const float4* __restrict__ w  = Wq + (size_t)(kq<<6)*256 + jg;
  #pragma unroll 4
  for (int kk=0; kk<16; ++kk){
    float4 h4 = hq[kk];
    float4 w0 = w[0];
    float4 w1 = w[256];
    float4 w2 = w[512];
    float4 w3 = w[768];
    ax += w0.x*h4.x; ay += w0.y*h4.x; az += w0.z*h4.x; aw += w0.w*h4.x;
    ax += w1.x*h4.y; ay += w1.y*h4.y; az += w1.z*h4.y; aw += w1.w*h4.y;
    ax += w2.x*h4.z; ay += w2.y*h4.z; az += w2.z*h4.z; aw += w2.w*h4.z;
    ax += w3.x*h4.w; ay += w3.y*h4.w; az += w3.z*h4.w; aw += w3.w*h4.w;
    w += 1024;
  }
  return make_float4(ax,ay,az,aw);
}

// --------------------------- encoder pipe (R8) -------------------------------
__global__ __launch_bounds__(1024) void k_pipe(
    const float* __restrict__ xp, int nsteps,
    const float* __restrict__ WT0, const float* __restrict__ WT1i,
    const float* __restrict__ WT1h, const float* __restrict__ b1,
    float* __restrict__ h0P, float* __restrict__ h1P,
    float* __restrict__ c0P, float* __restrict__ c1P,
    float* __restrict__ h0R, float* __restrict__ p1R,
    int* __restrict__ fA, int* __restrict__ fB1, int* __restrict__ fB2,
    int fbase, int initzero)
{
  __shared__ __align__(16) float part[4][4096];
  __shared__ float xps[1024];
  __shared__ __align__(16) float hloc[256];
  __shared__ float padL[4096];
  const int tid  = threadIdx.x;
  const int kq   = tid >> 8, jg = tid & 255;
  const int role = blockIdx.x >> 6;
  const int r    = blockIdx.x & 63;
  if (nsteps < 0){ padL[tid] = xp[tid]; h0R[tid] = padL[tid ^ 1]; }

  if (role == 0){
    float c0 = 0.f;
    if (tid < HID){
      if (initzero){ c0 = 0.f; hloc[tid] = 0.f; }
      else { c0 = c0P[tid*64 + r]; hloc[tid] = h0P[tid*64 + r]; }
    }
    __syncthreads();
    const float4* W4 = (const float4*)WT0;
    for (int q = 0; q < nsteps; ++q){
      float xv = xp[((size_t)q*64 + r)*G4 + tid];   // coalesced 4KB
      if (tid == 0 && q >= 4){
        int tgt = fbase + q - 3, g = 0;
        while (gload32(fB1 + r) < tgt && ++g < (1<<24)) {}
      }
      float4 a = dotpart(W4, hloc, kq, jg);
      xps[tid] = xv;
      *(float4*)&part[kq][jg<<2] = a;
      __syncthreads();
      if (tid < HID){
        float g0 = part[0][tid]+part[1][tid]+part[2][tid]+part[3][tid] + xps[tid];
        float g1 = part[0][HID+tid]+part[1][HID+tid]+part[2][HID+tid]+part[3][HID+tid] + xps[HID+tid];
        float g2 = part[0][2*HID+tid]+part[1][2*HID+tid]+part[2][2*HID+tid]+part[3][2*HID+tid] + xps[2*HID+tid];
        float g3 = part[0][3*HID+tid]+part[1][3*HID+tid]+part[2][3*HID+tid]+part[3][3*HID+tid] + xps[3*HID+tid];
        c0 = sigf(g1)*c0 + sigf(g0)*tanhf(g2);
        float h = sigf(g3)*tanhf(c0);
        hloc[tid] = h;
        gstoref(h0R + (q&3)*16384 + r*256 + tid, h);
        asm volatile("s_waitcnt vmcnt(0)" ::: "memory");
      }
      __syncthreads();
      if (tid == 0) gstorei(fA + r, fbase + q + 1);
    }
    if (tid < HID){ c0P[tid*64 + r] = c0; h0P[tid*64 + r] = hloc[tid]; }
  }
  else if (role == 1){
    const float4* W4 = (const float4*)WT1i;
    for (int q = 0; q < nsteps; ++q){
      if (tid == 0){
        int tgt = fbase + q + 1, g = 0;
        while (gload32(fA + r) < tgt && ++g < (1<<24)) {}
        if (q >= 4){
          int t2 = fbase + q - 3; g = 0;
          while (gload32(fB2 + r) < t2 && ++g < (1<<24)) {}
        }
      }
      __syncthreads();
      if (tid < HID) hloc[tid] = gloadf(h0R + (q&3)*16384 + r*256 + tid);
      __syncthreads();
      float4 a = dotpart(W4, hloc, kq, jg);
      *(float4*)&part[kq][jg<<2] = a;
      __syncthreads();
      float p = part[0][tid]+part[1][tid]+part[2][tid]+part[3][tid];
      gstoref(p1R + (q&3)*65536 + r*1024 + tid, p);
      asm volatile("s_waitcnt vmcnt(0)" ::: "memory");
      __syncthreads();
      if (tid == 0) gstorei(fB1 + r, fbase + q + 1);
    }
  }
  else {
    float c1 = 0.f, bb0=0.f, bb1=0.f, bb2=0.f, bb3=0.f;
    if (tid < HID){
      bb0 = b1[tid]; bb1 = b1[HID+tid]; bb2 = b1[2*HID+tid]; bb3 = b1[3*HID+tid];
      if (initzero){ c1 = 0.f; hloc[tid] = 0.f; }
      else { c1 = c1P[tid*64 + r]; hloc[tid] = h1P[tid*64 + r]; }
    }
    __syncthreads();
    const float4* W4 = (const float4*)WT1h;
    for (int q = 0; q < nsteps; ++q){
      if (tid == 0){
        int tgt = fbase + q + 1, g = 0;
        while (gload32(fB1 + r) < tgt && ++g < (1<<24)) {}
      }
      __syncthreads();
      xps[tid] = gloadf(p1R + (q&3)*65536 + r*1024 + tid);
      asm volatile("s_waitcnt vmcnt(0)" ::: "memory");
      __syncthreads();
      if (tid == 0) gstorei(fB2 + r, fbase + q + 1);
      float4 a = dotpart(W4, hloc, kq, jg);
      *(float4*)&part[kq][jg<<2] = a;
      __syncthreads();
      if (tid < HID){
        float g0 = part[0][tid]+part[1][tid]+part[2][tid]+part[3][tid] + xps[tid] + bb0;
        float g1 = part[0][HID+tid]+part[1][HID+tid]+part[2][HID+tid]+part[3][HID+tid] + xps[HID+tid] + bb1;
        float g2 = part[0][2*HID+tid]+part[1][2*HID+tid]+part[2][2*HID+tid]+part[3][2*HID+tid] + xps[2*HID+tid] + bb2;
        float g3 = part[0][3*HID+tid]+part[1][3*HID+tid]+part[2][3*HID+tid]+part[3][3*HID+tid] + xps[3*HID+tid] + bb3;
        c1 = sigf(g1)*c1 + sigf(g0)*tanhf(g2);
        float h = sigf(g3)*tanhf(c1);
        hloc[tid] = h;
        if (q == nsteps-1) h1P[tid*64 + r] = h;
      }
      __syncthreads();
    }
    if (tid < HID) c1P[tid*64 + r] = c1;
  }
}

// ------------------------- persistent decoder --------------------------------
// flags: fA[0..63] fB1[64..127] fB2[128..191] fH[192..255] fP[256..319]
//        fX[320..383] fT[384]
// WG mapping: xcd = bid&7 (round-robin dispatch), role = xcd>>1,
//             r = (xcd&1)*32 + (bid>>3).  A=XCD0-1 B1=2-3 B2=4-5 P=6-7.
__global__ __launch_bounds__(1024) void k_megadec(
    float* xp,                             // xp_d [32][64][1024] (RW)
    const float* __restrict__ WT0, const float* __restrict__ WT1i,
    const float* __restrict__ WT1h, const float* __restrict__ b1,
    const float* __restrict__ Wih0, const float* __restrict__ b0,
    const float* __restrict__ emb,
    const float* __restrict__ Wout, const float* __restrict__ bout,
    float* __restrict__ dout,
    const float* __restrict__ h0P, const float* __restrict__ h1P,
    const float* __restrict__ c0P, const float* __restrict__ c1P,
    float* __restrict__ h0R, float* __restrict__ p1R, float* __restrict__ h1R,
    float* __restrict__ pPv, int* __restrict__ pPi, float* __restrict__ xeG,
    int* __restrict__ flags)
{
  __shared__ __align__(16) float part[4][4096];   // 64 KB
  __shared__ float xps[1024];                     //  4 KB
  __shared__ __align__(16) float hloc[256];       //  1 KB
  __shared__ int   iscr[1024];                    //  4 KB
  __shared__ float htp[256*65];                   // 65 KB (padded [k][r])

  int* fA = flags;        int* fB1 = flags + 64;  int* fB2 = flags + 128;
  int* fH = flags + 192;  int* fP  = flags + 256; int* fX  = flags + 320;
  int* fT = flags + 384;

  const int tid  = threadIdx.x;
  const int lane = tid & 63;
  const int wv   = __builtin_amdgcn_readfirstlane(tid >> 6);
  const int kq   = tid >> 8, jg = tid & 255;
  const int xcd  = blockIdx.x & 7;
  const int role = xcd >> 1;
  const int r    = ((xcd & 1) << 5) | (blockIdx.x >> 3);   // 0..63

  // =========================== role A: layer 0 =============================
  if (role == 0){
    float c0 = 0.f;
    if (tid < HID){ c0 = c0P[tid*64 + r]; hloc[tid] = h0P[tid*64 + r]; }
    __syncthreads();
    const float4* W4 = (const float4*)WT0;
    int cum = 0;
    for (int t = 0; t < NPRED; ++t)
    for (int p = 0; p <= t; ++p, ++cum){
      if (wv == 0){
        if (lane == 0 && cum >= 4){
          int tgt = FBASE + cum - 3, g = 0;
          while (gload32(fB1 + r) < tgt && ++g < (1<<24)) {}
        }
        if (p == t && t >= 1){
          int g = 0;
          while (!__all(gload32(fX + lane) >= t) && ++g < (1<<24)) {}
        }
      }
      __syncthreads();
      const float* xa = xp + ((size_t)p*64 + r)*G4 + tid;   // coalesced
      float xv = (p == t) ? gloadf(xa) : *xa;   // sc1 first touch only
      float4 a = dotpart(W4, hloc, kq, jg);
      xps[tid] = xv;
      *(float4*)&part[kq][jg<<2] = a;
      __syncthreads();
      if (tid < HID){
        float g0 = part[0][tid]+part[1][tid]+part[2][tid]+part[3][tid] + xps[tid];
        float g1 = part[0][HID+tid]+part[1][HID+tid]+part[2][HID+tid]+part[3][HID+tid] + xps[HID+tid];
        float g2 = part[0][2*HID+tid]+part[1][2*HID+tid]+part[2][2*HID+tid]+part[3][2*HID+tid] + xps[2*HID+tid];
        float g3 = part[0][3*HID+tid]+part[1][3*HID+tid]+part[2][3*HID+tid]+part[3][3*HID+tid] + xps[3*HID+tid];
        c0 = sigf(g1)*c0 + sigf(g0)*tanhf(g2);
        float h = sigf(g3)*tanhf(c0);
        hloc[tid] = h;
        gstoref(h0R + (cum&3)*16384 + r*256 + tid, h);
        asm volatile("s_waitcnt vmcnt(0)" ::: "memory");
      }
      __syncthreads();
      if (tid == 0) gstorei(fA + r, FBASE + cum + 1);
    }
  }
  // =========================== role B1: Wih1.h0 ============================
  else if (role == 1){
    const float4* W4 = (const float4*)WT1i;
    int cum = 0;
    for (int t = 0; t < NPRED; ++t)
    for (int p = 0; p <= t; ++p, ++cum){
      if (tid == 0){
        int tgt = FBASE + cum + 1, g = 0;
        while (gload32(fA + r) < tgt && ++g < (1<<24)) {}
        if (cum >= 4){
          int t2 = FBASE + cum - 3; g = 0;
          while (gload32(fB2 + r) < t2 && ++g < (1<<24)) {}
        }
      }
      __syncthreads();
      if (tid < HID) hloc[tid] = gloadf(h0R + (cum&3)*16384 + r*256 + tid);
      __syncthreads();
      float4 a = dotpart(W4, hloc, kq, jg);
      *(float4*)&part[kq][jg<<2] = a;
      __syncthreads();
      float pp = part[0][tid]+part[1][tid]+part[2][tid]+part[3][tid];
      gstoref(p1R + (cum&3)*65536 + r*1024 + tid, pp);
      asm volatile("s_waitcnt vmcnt(0)" ::: "memory");
      __syncthreads();
      if (tid == 0) gstorei(fB1 + r, FBASE + cum + 1);
    }
  }
  // ================== role B2: Whh1.h1 + combine + act =====================
  else if (role == 2){
    float c1 = 0.f, bb0=0.f, bb1=0.f, bb2=0.f, bb3=0.f;
    if (tid < HID){
      bb0 = b1[tid]; bb1 = b1[HID+tid]; bb2 = b1[2*HID+tid]; bb3 = b1[3*HID+tid];
      c1 = c1P[tid*64 + r]; hloc[tid] = h1P[tid*64 + r];
    }
    __syncthreads();
    const float4* W4 = (const float4*)WT1h;
    int cum = 0;
    for (int t = 0; t < NPRED; ++t)
    for (int p = 0; p <= t; ++p, ++cum){
      if (tid == 0){
        int tgt = FBASE + cum + 1, g = 0;
        while (gload32(fB1 + r) < tgt && ++g < (1<<24)) {}
      }
      __syncthreads();
      xps[tid] = gloadf(p1R + (cum&3)*65536 + r*1024 + tid);
      asm volatile("s_waitcnt vmcnt(0)" ::: "memory");
      __syncthreads();
      if (tid == 0) gstorei(fB2 + r, FBASE + cum + 1);
      float4 a = dotpart(W4, hloc, kq, jg);
      *(float4*)&part[kq][jg<<2] = a;
      __syncthreads();
      if (tid < HID){
        float g0 = part[0][tid]+part[1][tid]+part[2][tid]+part[3][tid] + xps[tid] + bb0;
        float g1 = part[0][HID+tid]+part[1][HID+tid]+part[2][HID+tid]+part[3][HID+tid] + xps[HID+tid] + bb1;
        float g2 = part[0][2*HID+tid]+part[1][2*HID+tid]+part[2][2*HID+tid]+part[3][2*HID+tid] + xps[2*HID+tid] + bb2;
        float g3 = part[0][3*HID+tid]+part[1][3*HID+tid]+part[2][3*HID+tid]+part[3][3*HID+tid] + xps[3*HID+tid] + bb3;
        c1 = sigf(g1)*c1 + sigf(g0)*tanhf(g2);
        float h = sigf(g3)*tanhf(c1);
        hloc[tid] = h;
      }
      __syncthreads();
      if (p == t){
        if (tid == 0 && t >= 2){
          int g = 0;
          while (gload32(fT) < t - 1 && ++g < (1<<24)) {}
        }
        __syncthreads();
        if (tid < HID){
          gstoref(h1R + (t&1)*16384 + r*256 + tid, hloc[tid]);   // [r][k]
          asm volatile("s_waitcnt vmcnt(0)" ::: "memory");
        }
        __syncthreads();
        if (tid == 0) gstorei(fH + r, t + 1);
      }
    }
  }
  // ================== role P: pred + argmax + xproj ========================
  else {
    const int v  = r;                 // vocab slice id 0..63
    const int v0 = v * 500;
    const int rr = tid >> 4;          // 0..63  (row, for xproj)
    const int jl = tid & 15;          // 0..15  (j within slice)
    const float b0v = b0[v*16 + jl];

    for (int t = 0; t < NPRED; ++t){
      if (wv == 0){
        int g = 0;
        while (!__all(gload32(fH + lane) >= t+1) && ++g < (1<<24))
          __builtin_amdgcn_s_sleep(4);
      }
      if (tid == 0 && t >= 2){
        int g = 0;
        while (gload32(fT) < t - 1 && ++g < (1<<24)) {}
      }
      __syncthreads();
      // stage h1R[t&1] ([r][k]) -> htp[k*65+r]
      {
        const float* src = h1R + (size_t)(t&1)*16384;
        #pragma unroll
        for (int i=0;i<16;i++){
          int idx = tid + i*1024;
          float vl = gloadf(src + idx);
          htp[(idx & 255)*65 + (idx >> 8)] = vl;
        }
      }
      __syncthreads();
      // pred: wave wv, lane=row; vv = v0 + wv + 16*i (guard <500); cached Wout
      float best = -INFINITY; int bi = 0x7fffffff;
      for (int ib = 0; ib < 4; ++ib){
        float acc[8];
        #pragma unroll
        for (int jj=0;jj<8;jj++){
          int i = ib*8+jj;
          acc[jj] = (wv + 16*i < 500) ? bout[v0 + wv + 16*i] : 0.f;
        }
        for (int kc = 0; kc < 16; ++kc){
          float x[16];
          #pragma unroll
          for (int u=0;u<16;u++) x[u] = htp[(kc*16+u)*65 + lane];
          #pragma unroll
          for (int jj=0;jj<8;jj++){
            int i = ib*8+jj;
            if (wv + 16*i < 500){
              const float* Wp = Wout + (size_t)(v0 + wv + 16*i)*HID + kc*16;
              #pragma unroll
              for (int u=0;u<16;u++) acc[jj] += Wp[u]*x[u];
            }
          }
        }
        #pragma unroll
        for (int jj=0;jj<8;jj++){
          int i = ib*8+jj;
          if (wv + 16*i < 500){
            int vv = v0 + wv + 16*i;
            dout[((size_t)lane*NPRED + t)*VOC + vv] = acc[jj];   // cached store
            if (acc[jj] > best){ best = acc[jj]; bi = vv; }
          }
        }
      }
      xps[wv*64 + lane] = best; iscr[wv*64 + lane] = bi;
      __syncthreads();
      if (wv == 0){
        float bb = xps[lane]; int bbi = iscr[lane];
        #pragma unroll
        for (int w=1; w<16; w++){
          float vl = xps[w*64+lane]; int ii = iscr[w*64+lane];
          if (vl > bb || (vl == bb && ii < bbi)){ bb = vl; bbi = ii; }
        }
        gstoref(pPv + (t&1)*4096 + v*64 + lane, bb);
        gstorei(pPi + (t&1)*4096 + v*64 + lane, bbi);
        asm volatile("s_waitcnt vmcnt(0)" ::: "memory");
      }
      __syncthreads();
      if (tid == 0) gstorei(fP + v, t + 1);
      if (t == NPRED-1) continue;

      // ---- reducer (P0): global argmax (v ascending) + stage emb rows
      if (v == 0){
        if (wv == 0){
          int g = 0;
          while (!__all(gload32(fP + lane) >= t+1) && ++g < (1<<24)) {}
        }
        __syncthreads();
        {
          float bb = -INFINITY; int bbi = 0x7fffffff;
          #pragma unroll
          for (int i=0;i<4;i++){
            int vs = wv*4 + i;
            float vl = gloadf(pPv + (t&1)*4096 + vs*64 + lane);
            int  ii  = gload32(pPi + (t&1)*4096 + vs*64 + lane);
            if (vl > bb || (vl == bb && ii < bbi)){ bb = vl; bbi = ii; }
          }
          xps[wv*64+lane] = bb; iscr[wv*64+lane] = bbi;
        }
        __syncthreads();
        if (wv == 0){
          float bb = xps[lane]; int bbi = iscr[lane];
          #pragma unroll
          for (int w=1; w<16; w++){
            float vl = xps[w*64+lane]; int ii = iscr[w*64+lane];
            if (vl > bb || (vl == bb && ii < bbi)){ bb = vl; bbi = ii; }
          }
          iscr[lane] = bbi;           // token for row = lane
        }
        __syncthreads();
        {
          int tk = iscr[tid & 63];
          int r2 = tid & 63, kb = (tid >> 6) * 16;
          const float* er = emb + (size_t)tk*EMBD + kb;
          #pragma unroll
          for (int i=0;i<16;i++) gstoref(xeG + (kb+i)*64 + r2, er[i]);
          asm volatile("s_waitcnt vmcnt(0)" ::: "memory");
        }
        __syncthreads();
        if (tid == 0) gstorei(fT, t + 1);
      }

      // ---- xproj of position t+1 (all P WGs; j-slice of 16)
      if (tid == 0){
        int g = 0;
        while (gload32(fT) < t + 1 && ++g < (1<<24))
          __builtin_amdgcn_s_sleep(2);
      }
      __syncthreads();
      {
        #pragma unroll
        for (int i=0;i<16;i++){
          int idx = tid + i*1024;               // idx = k*64 + r
          htp[(idx >> 6)*65 + (idx & 63)] = gloadf(xeG + idx);
        }
      }
      __syncthreads();
      {
        int j  = v*16 + jl;
        const float* Wj = Wih0 + (size_t)j*EMBD;
        float acc = b0v;
        #pragma unroll 16
        for (int k=0;k<256;k++) acc += Wj[k]*htp[k*65 + rr];
        gstoref(xp + ((size_t)(t+1)*64 + rr)*G4 + v*16 + jl, acc);
        asm volatile("s_waitcnt vmcnt(0)" ::: "memory");
      }
      __syncthreads();
      if (tid == 0) gstorei(fX + v, t + 1);
    }
  }
}

// -------------------------------- launch ------------------------------------
extern "C" void kernel_launch(void* const* d_in, const int* in_sizes, int n_in,
                              void* d_out, int out_size, void* d_ws, size_t ws_size,
                              hipStream_t stream)
{
  const int*   input_seq  = (const int*)d_in[0];
  const int*   target_seq = (const int*)d_in[1];
  const float* enc_emb = (const float*)d_in[2];
  const float* dec_emb = (const float*)d_in[3];
  const float* enc_Wih = (const float*)d_in[4];
  const float* enc_Whh = (const float*)d_in[5];
  const float* enc_b   = (const float*)d_in[6];
  const float* dec_Wih = (const float*)d_in[7];
  const float* dec_Whh = (const float*)d_in[8];
  const float* dec_b   = (const float*)d_in[9];
  const float* W_out   = (const float*)d_in[10];
  const float* b_out   = (const float*)d_in[11];
  float* out = (float*)d_out;

  float* ws   = (float*)d_ws;
  float* xp_e = ws;                               // 64*64*1024
  float* xp_d = xp_e + (size_t)SLEN*64*G4;        // 32*64*1024
  float* h0P  = xp_d + (size_t)TLEN*64*G4;        // 256*64
  float* h1P  = h0P + HID*64;
  float* c0P  = h1P + HID*64;
  float* c1P  = c0P + HID*64;
  float* h0R  = c1P + HID*64;                     // 4*16384
  float* p1R  = h0R + 4*16384;                    // 4*65536
  float* h1R  = p1R + 4*65536;                    // 2*16384
  float* pPv  = h1R + 2*16384;                    // 2*4096
  int*   pPi  = (int*)(pPv + 2*4096);             // 2*4096
  float* xeG  = (float*)(pPi + 2*4096);           // 16384
  int*   flags= (int*)(xeG + 16384);              // 512
  float* WT0  = (float*)(flags + 512);            // 3 * 256*1024
  float* WT1i = WT0  + HID*G4;
  float* WT1h = WT1i + HID*G4;

  k_zero<<<1, 512, 0, stream>>>(flags);

  dim3 trg(16, 4);
  // encoder
  k_tr<<<trg, 256, 0, stream>>>(enc_Whh,                   WT0);
  k_tr<<<trg, 256, 0, stream>>>(enc_Wih + (size_t)G4*EMBD, WT1i);
  k_tr<<<trg, 256, 0, stream>>>(enc_Whh + (size_t)G4*HID,  WT1h);
  k_xproj<<<dim3(32, SLEN), 256, 0, stream>>>(input_seq, SLEN, 0, enc_emb,
        enc_Wih, enc_b, xp_e);
  k_pipe<<<192, 1024, 0, stream>>>(xp_e, SLEN,
        WT0, WT1i, WT1h, enc_b + G4,
        h0P, h1P, c0P, c1P, h0R, p1R,
        flags, flags + 64, flags + 128, 0, 1);

  // decoder weights + BOS xproj (position 0)
  k_tr<<<trg, 256, 0, stream>>>(dec_Whh,                   WT0);
  k_tr<<<trg, 256, 0, stream>>>(dec_Wih + (size_t)G4*EMBD, WT1i);
  k_tr<<<trg, 256, 0, stream>>>(dec_Whh + (size_t)G4*HID,  WT1h);
  k_xproj<<<dim3(32, 1), 256, 0, stream>>>(target_seq, TLEN, 0, dec_emb,
        dec_Wih, dec_b, xp_d);

  // persistent decoder
  k_megadec<<<256, 1024, 0, stream>>>(xp_d,
        WT0, WT1i, WT1h, dec_b + G4,
        dec_Wih, dec_b, dec_emb, W_out, b_out, out,
        h0P, h1P, c0P, c1P,
        h0R, p1R, h1R, pPv, pPi, xeG, flags);
}